// Round 14
// baseline (423.299 us; speedup 1.0000x reference)
//
#include <hip/hip_runtime.h>
#include <math.h>

#define H_HERBS 25000
#define DIM 128
#define SCAP 1024

typedef __attribute__((ext_vector_type(8))) short bf16x8;
typedef __attribute__((ext_vector_type(4))) float f32x4;

__device__ inline unsigned pack2bf(float a, float b) {
    union { float f; unsigned u; } x, y; x.f = a; y.f = b;
    return ((x.u + 0x8000u) >> 16) | ((y.u + 0x8000u) & 0xFFFF0000u);
}

// ---------------- K1: segment starts via binary search (indices sorted) ---
__global__ void k_starts(const int* __restrict__ idxA, const int* __restrict__ idxB,
                         int nA, int nB, int* __restrict__ startA, int* __restrict__ startB) {
    int h = blockIdx.x * blockDim.x + threadIdx.x;
    if (h > H_HERBS) return;
    {
        int lo = 0, hi = nA;
        while (lo < hi) { int mid = (lo + hi) >> 1; if (idxA[mid] < h) lo = mid + 1; else hi = mid; }
        startA[h] = lo;
    }
    {
        int lo = 0, hi = nB;
        while (lo < hi) { int mid = (lo + hi) >> 1; if (idxB[mid] < h) lo = mid + 1; else hi = mid; }
        startB[h] = lo;
    }
}

// ---------------- K1b: pre-pack fw1/fw2 into bf16 MFMA B-fragment order ---
__global__ __launch_bounds__(64) void k_packw(
        const float* __restrict__ fw1, const float* __restrict__ fw2,
        uint4* __restrict__ w1bf, uint4* __restrict__ w2bf) {
    int b = blockIdx.x, l = threadIdx.x;
    int c = l & 15, kg = l >> 4;
    if (b < 256) {                       // fw1 [512][256]: 16 kt x 16 nt
        int kt = b >> 4, nt = b & 15;
        int k0 = kt * 32 + kg * 8, j = nt * 16 + c;
        unsigned u0 = pack2bf(fw1[(size_t)(k0 + 0) * 256 + j], fw1[(size_t)(k0 + 1) * 256 + j]);
        unsigned u1 = pack2bf(fw1[(size_t)(k0 + 2) * 256 + j], fw1[(size_t)(k0 + 3) * 256 + j]);
        unsigned u2 = pack2bf(fw1[(size_t)(k0 + 4) * 256 + j], fw1[(size_t)(k0 + 5) * 256 + j]);
        unsigned u3 = pack2bf(fw1[(size_t)(k0 + 6) * 256 + j], fw1[(size_t)(k0 + 7) * 256 + j]);
        w1bf[(size_t)b * 64 + l] = make_uint4(u0, u1, u2, u3);
    } else {                             // fw2 [256][128]: 8 kt x 8 nt
        int bb = b - 256;
        int kt = bb >> 3, nt = bb & 7;
        int k0 = kt * 32 + kg * 8, j = nt * 16 + c;
        unsigned u0 = pack2bf(fw2[(size_t)(k0 + 0) * 128 + j], fw2[(size_t)(k0 + 1) * 128 + j]);
        unsigned u1 = pack2bf(fw2[(size_t)(k0 + 2) * 128 + j], fw2[(size_t)(k0 + 3) * 128 + j]);
        unsigned u2 = pack2bf(fw2[(size_t)(k0 + 4) * 128 + j], fw2[(size_t)(k0 + 5) * 128 + j]);
        unsigned u3 = pack2bf(fw2[(size_t)(k0 + 6) * 128 + j], fw2[(size_t)(k0 + 7) * 128 + j]);
        w2bf[(size_t)bb * 64 + l] = make_uint4(u0, u1, u2, u3);
    }
}

// ---------------- K2: mean + projection for ONE side, 16 herbs / block ----
__global__ __launch_bounds__(256) void k_mean_proj(
        const float* __restrict__ X, const int* __restrict__ start,
        const float* __restrict__ aw1, const float* __restrict__ ab1,
        float* __restrict__ mpart) {
    __shared__ float Wl[128 * 64];                 // 32 KB
    __shared__ __align__(16) float mb[16][128];    // 8 KB
    int h0 = blockIdx.x * 16;
    int t = threadIdx.x;

    {
        const float4* Wsrc = (const float4*)(aw1 + 128 * 64);
        float4* Wl4 = (float4*)Wl;
        #pragma unroll
        for (int q = 0; q < 8; ++q) Wl4[t + 256 * q] = Wsrc[t + 256 * q];
    }

    int wv = t >> 6, ln = t & 63, half = ln >> 5, li = ln & 31;
    const float4* X4 = (const float4*)X;
    #pragma unroll
    for (int i = 0; i < 4; ++i) {
        int hh = wv * 4 + i;
        int h = h0 + hh;
        if (h >= H_HERBS) { if (half == 0) ((float4*)mb[hh])[li] = make_float4(0.f,0.f,0.f,0.f); continue; }
        int s = start[h], e = start[h + 1];
        float4 acc = make_float4(0.f, 0.f, 0.f, 0.f);
        int r = s + half;
        for (; r + 6 < e; r += 8) {
            float4 v0 = X4[(size_t)r * 32 + li];
            float4 v1 = X4[(size_t)(r + 2) * 32 + li];
            float4 v2 = X4[(size_t)(r + 4) * 32 + li];
            float4 v3 = X4[(size_t)(r + 6) * 32 + li];
            acc.x += (v0.x + v1.x) + (v2.x + v3.x);
            acc.y += (v0.y + v1.y) + (v2.y + v3.y);
            acc.z += (v0.z + v1.z) + (v2.z + v3.z);
            acc.w += (v0.w + v1.w) + (v2.w + v3.w);
        }
        for (; r < e; r += 2) {
            float4 v0 = X4[(size_t)r * 32 + li];
            acc.x += v0.x; acc.y += v0.y; acc.z += v0.z; acc.w += v0.w;
        }
        acc.x += __shfl_xor(acc.x, 32, 64);
        acc.y += __shfl_xor(acc.y, 32, 64);
        acc.z += __shfl_xor(acc.z, 32, 64);
        acc.w += __shfl_xor(acc.w, 32, 64);
        int cnt = e - s;
        float inv = 1.0f / (float)(cnt > 1 ? cnt : 1);
        if (half == 0) {
            ((float4*)mb[hh])[li] = make_float4(acc.x * inv, acc.y * inv, acc.z * inv, acc.w * inv);
        }
    }
    __syncthreads();

    {
        int j = t & 63, wg = t >> 6;
        float b1 = ab1[j];
        float a0 = b1, a1 = b1, a2 = b1, a3 = b1;
        #pragma unroll 8
        for (int k = 0; k < 128; ++k) {
            float w = Wl[k * 64 + j];
            a0 += mb[wg * 4 + 0][k] * w;
            a1 += mb[wg * 4 + 1][k] * w;
            a2 += mb[wg * 4 + 2][k] * w;
            a3 += mb[wg * 4 + 3][k] * w;
        }
        int h = h0 + wg * 4;
        if (h + 0 < H_HERBS) mpart[(size_t)(h + 0) * 64 + j] = a0;
        if (h + 1 < H_HERBS) mpart[(size_t)(h + 1) * 64 + j] = a1;
        if (h + 2 < H_HERBS) mpart[(size_t)(h + 2) * 64 + j] = a2;
        if (h + 3 < H_HERBS) mpart[(size_t)(h + 3) * 64 + j] = a3;
    }
}

// ---------------- K2b: mpart from precomputed mean (one side) -------------
__global__ __launch_bounds__(256) void k_mpart_one(
        const float* __restrict__ meanG, const float* __restrict__ aw1,
        const float* __restrict__ ab1, float* __restrict__ mpart) {
    __shared__ float Wl[128 * 64];
    __shared__ float mb[64 * 128];
    int h0 = blockIdx.x * 64;
    int t = threadIdx.x;

    const float4* Wsrc = (const float4*)(aw1 + 128 * 64);
    float4* Wl4 = (float4*)Wl;
    #pragma unroll
    for (int q = 0; q < 8; ++q) Wl4[t + 256 * q] = Wsrc[t + 256 * q];
    float4* mb4 = (float4*)mb;
    const float4* mG4 = (const float4*)meanG;
    #pragma unroll
    for (int q = 0; q < 8; ++q) {
        int ent = t + 256 * q;
        int hl = ent >> 5, kq = ent & 31;
        int h = h0 + hl;
        mb4[ent] = (h < H_HERBS) ? mG4[(size_t)h * 32 + kq] : make_float4(0.f, 0.f, 0.f, 0.f);
    }
    __syncthreads();

    int j = t & 63, hg = t >> 6;
    float b1 = ab1[j];
    #pragma unroll
    for (int ii = 0; ii < 4; ++ii) {
        int hl0 = hg * 16 + ii * 4;
        float a0 = 0.f, a1 = 0.f, a2 = 0.f, a3 = 0.f;
        for (int k = 0; k < 128; ++k) {
            float w = Wl[k * 64 + j];
            a0 += mb[(hl0 + 0) * 128 + k] * w;
            a1 += mb[(hl0 + 1) * 128 + k] * w;
            a2 += mb[(hl0 + 2) * 128 + k] * w;
            a3 += mb[(hl0 + 3) * 128 + k] * w;
        }
        int h = h0 + hl0;
        if (h + 0 < H_HERBS) mpart[(size_t)(h + 0) * 64 + j] = b1 + a0;
        if (h + 1 < H_HERBS) mpart[(size_t)(h + 1) * 64 + j] = b1 + a1;
        if (h + 2 < H_HERBS) mpart[(size_t)(h + 2) * 64 + j] = b1 + a2;
        if (h + 3 < H_HERBS) mpart[(size_t)(h + 3) * 64 + j] = b1 + a3;
    }
}

// ---------------- K3: fused MFMA scores + softmax + weighted sum ----------
// Block = 16 consecutive herbs (~320 contiguous rows). Phase A: 16-row MFMA
// score tiles, wave-cyclic (non-redundant), scores -> LDS. Phase B: per-herb
// max/exp/sum in LDS (invden saved). Phase C: weighted sum re-reading the
// block's X rows (L1/L2-hot from phase A); side A also accumulates mean.
template <bool WITH_MEAN>
__global__ __launch_bounds__(256) void k_seg_attn_mfma(
        const float* __restrict__ X, const int* __restrict__ idx,
        const int* __restrict__ start, const float* __restrict__ mpart,
        const float* __restrict__ aw1, const float* __restrict__ aw2,
        const float* __restrict__ ab2,
        float* __restrict__ out, float* __restrict__ meanOut) {
    __shared__ float sc[SCAP];
    __shared__ float invden_s[16];

    int t = threadIdx.x;
    int wv = t >> 6, l = t & 63;
    int c = l & 15, kg = l >> 4;

    int h0 = blockIdx.x * 16;
    int nh = H_HERBS - h0; if (nh > 16) nh = 16;
    int rs = start[h0];
    int re = start[h0 + nh];
    int cnt = re - rs; if (cnt > SCAP) cnt = SCAP;

    union ABu { bf16x8 v; unsigned u[4]; };

    // W fragments (per-lane registers, same data across waves)
    ABu wf[4][4];
    #pragma unroll
    for (int kb = 0; kb < 4; ++kb) {
        int k0 = kb * 32 + kg * 8;
        #pragma unroll
        for (int nb = 0; nb < 4; ++nb) {
            int j = nb * 16 + c;
            #pragma unroll
            for (int e = 0; e < 4; ++e) {
                wf[kb][nb].u[e] = pack2bf(aw1[(size_t)(k0 + 2 * e)     * 64 + j],
                                          aw1[(size_t)(k0 + 2 * e + 1) * 64 + j]);
            }
        }
    }
    float a2[4];
    #pragma unroll
    for (int nb = 0; nb < 4; ++nb) a2[nb] = aw2[nb * 16 + c];
    float b2s = ab2[0];

    // ---- phase A: scores for 16-row tiles, wave-cyclic ----
    int ntiles = (cnt + 15) >> 4;
    for (int tile = wv; tile < ntiles; tile += 4) {
        int lr0 = tile * 16;
        int lrow = lr0 + c;
        int lrowc = lrow < cnt ? lrow : cnt - 1;
        const float4* Xr = (const float4*)(X + (size_t)(rs + lrowc) * DIM);

        ABu af[4];
        #pragma unroll
        for (int kb = 0; kb < 4; ++kb) {
            float4 a = Xr[kb * 8 + kg * 2];
            float4 b = Xr[kb * 8 + kg * 2 + 1];
            af[kb].u[0] = pack2bf(a.x, a.y);
            af[kb].u[1] = pack2bf(a.z, a.w);
            af[kb].u[2] = pack2bf(b.x, b.y);
            af[kb].u[3] = pack2bf(b.z, b.w);
        }

        f32x4 acc[4];
        #pragma unroll
        for (int nb = 0; nb < 4; ++nb) { acc[nb].x = 0.f; acc[nb].y = 0.f; acc[nb].z = 0.f; acc[nb].w = 0.f; }
        #pragma unroll
        for (int kb = 0; kb < 4; ++kb) {
            #pragma unroll
            for (int nb = 0; nb < 4; ++nb) {
                acc[nb] = __builtin_amdgcn_mfma_f32_16x16x32_bf16(af[kb].v, wf[kb][nb].v, acc[nb], 0, 0, 0);
            }
        }

        int rgrp = kg * 4;
        #pragma unroll
        for (int reg = 0; reg < 4; ++reg) {
            int rl = lr0 + rgrp + reg;
            bool v = rl < cnt;
            int h = v ? idx[rs + rl] : h0;
            const float* mp = mpart + (size_t)h * 64;
            float part = 0.f;
            #pragma unroll
            for (int nb = 0; nb < 4; ++nb) {
                float hv = acc[nb][reg] + mp[nb * 16 + c];
                hv = hv > 0.f ? hv : 0.2f * hv;
                part += hv * a2[nb];
            }
            part += __shfl_xor(part, 1, 64);
            part += __shfl_xor(part, 2, 64);
            part += __shfl_xor(part, 4, 64);
            part += __shfl_xor(part, 8, 64);
            if (c == 0 && v) sc[rl] = part + b2s;
        }
    }
    __syncthreads();

    // ---- phase B: per-herb max/exp/sum; sc <- exp(s-mx), invden saved ----
    for (int i = wv; i < nh; i += 4) {
        int h = h0 + i;
        int ls = start[h] - rs, le = start[h + 1] - rs;
        if (ls > cnt) ls = cnt;
        if (le > cnt) le = cnt;
        if (le <= ls) { if (l == 0) invden_s[i] = 0.f; continue; }
        float mx = -INFINITY;
        for (int r = ls + l; r < le; r += 64) mx = fmaxf(mx, sc[r]);
        #pragma unroll
        for (int o = 32; o; o >>= 1) mx = fmaxf(mx, __shfl_xor(mx, o, 64));
        float sum = 0.f;
        for (int r = ls + l; r < le; r += 64) {
            float e = __expf(sc[r] - mx);
            sc[r] = e;
            sum += e;
        }
        #pragma unroll
        for (int o = 32; o; o >>= 1) sum += __shfl_xor(sum, o, 64);
        if (l == 0) invden_s[i] = 1.0f / (sum + 1e-16f);
    }
    __syncthreads();

    // ---- phase C: weighted sum (X rows L1/L2-hot); side A adds mean ----
    const float4* X4 = (const float4*)X;
    int half = l >> 5, li = l & 31;
    for (int i = wv; i < nh; i += 4) {
        int h = h0 + i;
        int ls = start[h] - rs, le = start[h + 1] - rs;
        if (ls > cnt) ls = cnt;
        if (le > cnt) le = cnt;
        float4 acc = make_float4(0.f, 0.f, 0.f, 0.f);
        float4 accS = make_float4(0.f, 0.f, 0.f, 0.f);
        int r = ls + half;
        for (; r + 6 < le; r += 8) {
            float w0 = sc[r], w1 = sc[r + 2], w2 = sc[r + 4], w3 = sc[r + 6];
            float4 v0 = X4[(size_t)(rs + r) * 32 + li];
            float4 v1 = X4[(size_t)(rs + r + 2) * 32 + li];
            float4 v2 = X4[(size_t)(rs + r + 4) * 32 + li];
            float4 v3 = X4[(size_t)(rs + r + 6) * 32 + li];
            acc.x += (w0 * v0.x + w1 * v1.x) + (w2 * v2.x + w3 * v3.x);
            acc.y += (w0 * v0.y + w1 * v1.y) + (w2 * v2.y + w3 * v3.y);
            acc.z += (w0 * v0.z + w1 * v1.z) + (w2 * v2.z + w3 * v3.z);
            acc.w += (w0 * v0.w + w1 * v1.w) + (w2 * v2.w + w3 * v3.w);
            if (WITH_MEAN) {
                accS.x += (v0.x + v1.x) + (v2.x + v3.x);
                accS.y += (v0.y + v1.y) + (v2.y + v3.y);
                accS.z += (v0.z + v1.z) + (v2.z + v3.z);
                accS.w += (v0.w + v1.w) + (v2.w + v3.w);
            }
        }
        for (; r < le; r += 2) {
            float w0 = sc[r];
            float4 v0 = X4[(size_t)(rs + r) * 32 + li];
            acc.x += w0 * v0.x; acc.y += w0 * v0.y;
            acc.z += w0 * v0.z; acc.w += w0 * v0.w;
            if (WITH_MEAN) {
                accS.x += v0.x; accS.y += v0.y; accS.z += v0.z; accS.w += v0.w;
            }
        }
        acc.x += __shfl_xor(acc.x, 32, 64);
        acc.y += __shfl_xor(acc.y, 32, 64);
        acc.z += __shfl_xor(acc.z, 32, 64);
        acc.w += __shfl_xor(acc.w, 32, 64);
        if (WITH_MEAN) {
            accS.x += __shfl_xor(accS.x, 32, 64);
            accS.y += __shfl_xor(accS.y, 32, 64);
            accS.z += __shfl_xor(accS.z, 32, 64);
            accS.w += __shfl_xor(accS.w, 32, 64);
        }
        if (half == 0) {
            float inv = invden_s[i];
            ((float4*)out)[(size_t)h * 32 + li] =
                make_float4(acc.x * inv, acc.y * inv, acc.z * inv, acc.w * inv);
            if (WITH_MEAN) {
                int ch = le - ls;
                float im = 1.0f / (float)(ch > 1 ? ch : 1);
                ((float4*)meanOut)[(size_t)h * 32 + li] =
                    make_float4(accS.x * im, accS.y * im, accS.z * im, accS.w * im);
            }
        }
    }
}

// ---------------- K5: fusion MLP on matrix cores ---------------------------
__global__ __launch_bounds__(256) void k_fusion_mfma(
        const float* __restrict__ HA, const float* __restrict__ HB,
        const uint4* __restrict__ w1bf, const uint4* __restrict__ w2bf,
        const float* __restrict__ fb1, const float* __restrict__ fb2,
        float* __restrict__ out) {
    __shared__ float hid[32 * 256];   // 32 KB, swizzled
    int t = threadIdx.x, wid = t >> 6, l = t & 63, c = l & 15, kg = l >> 4;
    int h0 = blockIdx.x * 32;
    int ms = wid & 1, nh = wid >> 1;

    union ABu { bf16x8 v; unsigned u[4]; uint4 q; };

    {
        int rowl = ms * 16 + c;
        int h = h0 + rowl;
        bool hv = h < H_HERBS;
        const float* pa = HA + (size_t)(hv ? h : h0) * DIM;
        const float* pb = HB + (size_t)(hv ? h : h0) * DIM;

        f32x4 acc[8];
        #pragma unroll
        for (int nt = 0; nt < 8; ++nt) { acc[nt].x = 0.f; acc[nt].y = 0.f; acc[nt].z = 0.f; acc[nt].w = 0.f; }

        #pragma unroll
        for (int kt = 0; kt < 16; ++kt) {
            int k0 = kt * 32 + kg * 8;
            int range = k0 >> 7, off = k0 & 127;
            float f[8];
            if (range == 0) {
                float4 a0 = *(const float4*)(pa + off), a1 = *(const float4*)(pa + off + 4);
                f[0] = a0.x; f[1] = a0.y; f[2] = a0.z; f[3] = a0.w;
                f[4] = a1.x; f[5] = a1.y; f[6] = a1.z; f[7] = a1.w;
            } else if (range == 1) {
                float4 b0 = *(const float4*)(pb + off), b1 = *(const float4*)(pb + off + 4);
                f[0] = b0.x; f[1] = b0.y; f[2] = b0.z; f[3] = b0.w;
                f[4] = b1.x; f[5] = b1.y; f[6] = b1.z; f[7] = b1.w;
            } else if (range == 2) {
                float4 a0 = *(const float4*)(pa + off), a1 = *(const float4*)(pa + off + 4);
                float4 b0 = *(const float4*)(pb + off), b1 = *(const float4*)(pb + off + 4);
                f[0] = a0.x * b0.x; f[1] = a0.y * b0.y; f[2] = a0.z * b0.z; f[3] = a0.w * b0.w;
                f[4] = a1.x * b1.x; f[5] = a1.y * b1.y; f[6] = a1.z * b1.z; f[7] = a1.w * b1.w;
            } else {
                float4 a0 = *(const float4*)(pa + off), a1 = *(const float4*)(pa + off + 4);
                float4 b0 = *(const float4*)(pb + off), b1 = *(const float4*)(pb + off + 4);
                f[0] = fabsf(a0.x - b0.x); f[1] = fabsf(a0.y - b0.y);
                f[2] = fabsf(a0.z - b0.z); f[3] = fabsf(a0.w - b0.w);
                f[4] = fabsf(a1.x - b1.x); f[5] = fabsf(a1.y - b1.y);
                f[6] = fabsf(a1.z - b1.z); f[7] = fabsf(a1.w - b1.w);
            }
            ABu af;
            af.u[0] = pack2bf(f[0], f[1]); af.u[1] = pack2bf(f[2], f[3]);
            af.u[2] = pack2bf(f[4], f[5]); af.u[3] = pack2bf(f[6], f[7]);
            #pragma unroll
            for (int nt = 0; nt < 8; ++nt) {
                ABu bfr; bfr.q = w1bf[(size_t)(kt * 16 + nh * 8 + nt) * 64 + l];
                acc[nt] = __builtin_amdgcn_mfma_f32_16x16x32_bf16(af.v, bfr.v, acc[nt], 0, 0, 0);
            }
        }

        #pragma unroll
        for (int nt = 0; nt < 8; ++nt) {
            int j = nh * 128 + nt * 16 + c;
            float b1 = fb1[j];
            #pragma unroll
            for (int reg = 0; reg < 4; ++reg) {
                int row = ms * 16 + kg * 4 + reg;
                float v = fmaxf(acc[nt][reg] + b1, 0.f);
                hid[row * 256 + (j ^ ((row & 7) << 3))] = v;
            }
        }
    }
    __syncthreads();

    {
        int rowl = ms * 16 + c;
        f32x4 acc2[4];
        #pragma unroll
        for (int nt = 0; nt < 4; ++nt) { acc2[nt].x = 0.f; acc2[nt].y = 0.f; acc2[nt].z = 0.f; acc2[nt].w = 0.f; }

        #pragma unroll
        for (int kt = 0; kt < 8; ++kt) {
            int j0 = kt * 32 + kg * 8;
            int widx = rowl * 256 + (j0 ^ ((rowl & 7) << 3));
            float4 h0v = *(const float4*)&hid[widx];
            float4 h1v = *(const float4*)&hid[widx + 4];
            ABu af;
            af.u[0] = pack2bf(h0v.x, h0v.y); af.u[1] = pack2bf(h0v.z, h0v.w);
            af.u[2] = pack2bf(h1v.x, h1v.y); af.u[3] = pack2bf(h1v.z, h1v.w);
            #pragma unroll
            for (int nt = 0; nt < 4; ++nt) {
                ABu bfr; bfr.q = w2bf[(size_t)(kt * 8 + nh * 4 + nt) * 64 + l];
                acc2[nt] = __builtin_amdgcn_mfma_f32_16x16x32_bf16(af.v, bfr.v, acc2[nt], 0, 0, 0);
            }
        }

        #pragma unroll
        for (int nt = 0; nt < 4; ++nt) {
            int j = nh * 64 + nt * 16 + c;
            float b2 = fb2[j];
            #pragma unroll
            for (int reg = 0; reg < 4; ++reg) {
                int row = ms * 16 + kg * 4 + reg;
                int h = h0 + row;
                if (h < H_HERBS) out[(size_t)h * DIM + j] = acc2[nt][reg] + b2;
            }
        }
    }
}

extern "C" void kernel_launch(void* const* d_in, const int* in_sizes, int n_in,
                              void* d_out, int out_size, void* d_ws, size_t ws_size,
                              hipStream_t stream) {
    const float* hA  = (const float*)d_in[0];
    const float* hB  = (const float*)d_in[1];
    const int*   idxA = (const int*)d_in[2];
    const int*   idxB = (const int*)d_in[3];
    const float* aw1 = (const float*)d_in[5];
    const float* ab1 = (const float*)d_in[6];
    const float* aw2 = (const float*)d_in[7];
    const float* ab2 = (const float*)d_in[8];
    const float* fw1 = (const float*)d_in[9];
    const float* fb1 = (const float*)d_in[10];
    const float* fw2 = (const float*)d_in[11];
    const float* fb2 = (const float*)d_in[12];

    int nA = in_sizes[0] / DIM;
    int nB = in_sizes[1] / DIM;

    float* out  = (float*)d_out;
    float* outI = out;                                  // fusion output (last write)
    float* outA = out + (size_t)H_HERBS * DIM;
    float* outB = out + (size_t)2 * H_HERBS * DIM;
    float* meanA = outI;                                // scratch; overwritten by fusion

    char* w = (char*)d_ws;
    auto carve = [&](size_t bytes) { char* p = w; w += (bytes + 255) & ~(size_t)255; return p; };
    int*   startA  = (int*)carve((size_t)(H_HERBS + 1) * sizeof(int));
    int*   startB  = (int*)carve((size_t)(H_HERBS + 1) * sizeof(int));
    float* mpartA  = (float*)carve((size_t)H_HERBS * 64 * sizeof(float));
    float* mpartB  = (float*)carve((size_t)H_HERBS * 64 * sizeof(float));
    uint4* w1bf    = (uint4*)carve((size_t)256 * 64 * sizeof(uint4));   // 256 KB
    uint4* w2bf    = (uint4*)carve((size_t)64 * 64 * sizeof(uint4));    // 64 KB

    int nhb16 = (H_HERBS + 15) / 16;
    int nhb64 = (H_HERBS + 63) / 64;

    k_starts<<<(H_HERBS + 1 + 255) / 256, 256, 0, stream>>>(idxA, idxB, nA, nB, startA, startB);
    k_packw<<<320, 64, 0, stream>>>(fw1, fw2, w1bf, w2bf);

    // ---- side-sequential schedule for L3 residency ----
    // D1: meanB (reads XB cold) -> mpartA
    k_mean_proj<<<nhb16, 256, 0, stream>>>(hB, startB, aw1, ab1, mpartA);
    // D2: fused scores+softmax+attn for A (XA once; phase-C rows L1/L2-hot) + meanA
    k_seg_attn_mfma<true><<<nhb16, 256, 0, stream>>>(hA, idxA, startA, mpartA,
                                                     aw1, aw2, ab2, outA, meanA);
    // D3: mpartB from meanA (tiny)
    k_mpart_one<<<nhb64, 256, 0, stream>>>(meanA, aw1, ab1, mpartB);
    // D4: fused scores+softmax+attn for B (XB L3-hot)
    k_seg_attn_mfma<false><<<nhb16, 256, 0, stream>>>(hB, idxB, startB, mpartB,
                                                      aw1, aw2, ab2, outB, nullptr);
    // D5: fusion MLP (overwrites outI/meanA)
    k_fusion_mfma<<<(H_HERBS + 31) / 32, 256, 0, stream>>>(outA, outB, w1bf, w2bf, fb1, fb2, outI);
}

// Round 15
// 385.585 us; speedup vs baseline: 1.0978x; 1.0978x over previous
//
#include <hip/hip_runtime.h>
#include <math.h>

#define H_HERBS 25000
#define DIM 128

typedef __attribute__((ext_vector_type(8))) short bf16x8;
typedef __attribute__((ext_vector_type(4))) float f32x4;

__device__ inline unsigned pack2bf(float a, float b) {
    union { float f; unsigned u; } x, y; x.f = a; y.f = b;
    return ((x.u + 0x8000u) >> 16) | ((y.u + 0x8000u) & 0xFFFF0000u);
}

// ---------------- K1: segment starts via binary search (indices sorted) ---
__global__ void k_starts(const int* __restrict__ idxA, const int* __restrict__ idxB,
                         int nA, int nB, int* __restrict__ startA, int* __restrict__ startB) {
    int h = blockIdx.x * blockDim.x + threadIdx.x;
    if (h > H_HERBS) return;
    {
        int lo = 0, hi = nA;
        while (lo < hi) { int mid = (lo + hi) >> 1; if (idxA[mid] < h) lo = mid + 1; else hi = mid; }
        startA[h] = lo;
    }
    {
        int lo = 0, hi = nB;
        while (lo < hi) { int mid = (lo + hi) >> 1; if (idxB[mid] < h) lo = mid + 1; else hi = mid; }
        startB[h] = lo;
    }
}

// ---------------- K1b: pre-pack fw1/fw2 into bf16 MFMA B-fragment order ---
__global__ __launch_bounds__(64) void k_packw(
        const float* __restrict__ fw1, const float* __restrict__ fw2,
        uint4* __restrict__ w1bf, uint4* __restrict__ w2bf) {
    int b = blockIdx.x, l = threadIdx.x;
    int c = l & 15, kg = l >> 4;
    if (b < 256) {                       // fw1 [512][256]: 16 kt x 16 nt
        int kt = b >> 4, nt = b & 15;
        int k0 = kt * 32 + kg * 8, j = nt * 16 + c;
        unsigned u0 = pack2bf(fw1[(size_t)(k0 + 0) * 256 + j], fw1[(size_t)(k0 + 1) * 256 + j]);
        unsigned u1 = pack2bf(fw1[(size_t)(k0 + 2) * 256 + j], fw1[(size_t)(k0 + 3) * 256 + j]);
        unsigned u2 = pack2bf(fw1[(size_t)(k0 + 4) * 256 + j], fw1[(size_t)(k0 + 5) * 256 + j]);
        unsigned u3 = pack2bf(fw1[(size_t)(k0 + 6) * 256 + j], fw1[(size_t)(k0 + 7) * 256 + j]);
        w1bf[(size_t)b * 64 + l] = make_uint4(u0, u1, u2, u3);
    } else {                             // fw2 [256][128]: 8 kt x 8 nt
        int bb = b - 256;
        int kt = bb >> 3, nt = bb & 7;
        int k0 = kt * 32 + kg * 8, j = nt * 16 + c;
        unsigned u0 = pack2bf(fw2[(size_t)(k0 + 0) * 128 + j], fw2[(size_t)(k0 + 1) * 128 + j]);
        unsigned u1 = pack2bf(fw2[(size_t)(k0 + 2) * 128 + j], fw2[(size_t)(k0 + 3) * 128 + j]);
        unsigned u2 = pack2bf(fw2[(size_t)(k0 + 4) * 128 + j], fw2[(size_t)(k0 + 5) * 128 + j]);
        unsigned u3 = pack2bf(fw2[(size_t)(k0 + 6) * 128 + j], fw2[(size_t)(k0 + 7) * 128 + j]);
        w2bf[(size_t)bb * 64 + l] = make_uint4(u0, u1, u2, u3);
    }
}

// ---------------- K2: mean + projection for ONE side, 16 herbs / block ----
// No W staging (proven useless r11->r12; kernel is X-latency-bound). LDS 8KB
// -> high occupancy -> X sweep BW-bound. Projection reads aw1 from L2.
__global__ __launch_bounds__(256) void k_mean_proj(
        const float* __restrict__ X, const int* __restrict__ start,
        const float* __restrict__ aw1, const float* __restrict__ ab1,
        float* __restrict__ mpart) {
    __shared__ __align__(16) float mb[16][128];    // 8 KB
    int h0 = blockIdx.x * 16;
    int t = threadIdx.x;

    int wv = t >> 6, ln = t & 63, half = ln >> 5, li = ln & 31;
    const float4* X4 = (const float4*)X;
    #pragma unroll
    for (int i = 0; i < 4; ++i) {
        int hh = wv * 4 + i;
        int h = h0 + hh;
        if (h >= H_HERBS) { if (half == 0) ((float4*)mb[hh])[li] = make_float4(0.f,0.f,0.f,0.f); continue; }
        int s = start[h], e = start[h + 1];
        float4 acc = make_float4(0.f, 0.f, 0.f, 0.f);
        int r = s + half;
        for (; r + 6 < e; r += 8) {
            float4 v0 = X4[(size_t)r * 32 + li];
            float4 v1 = X4[(size_t)(r + 2) * 32 + li];
            float4 v2 = X4[(size_t)(r + 4) * 32 + li];
            float4 v3 = X4[(size_t)(r + 6) * 32 + li];
            acc.x += (v0.x + v1.x) + (v2.x + v3.x);
            acc.y += (v0.y + v1.y) + (v2.y + v3.y);
            acc.z += (v0.z + v1.z) + (v2.z + v3.z);
            acc.w += (v0.w + v1.w) + (v2.w + v3.w);
        }
        for (; r < e; r += 2) {
            float4 v0 = X4[(size_t)r * 32 + li];
            acc.x += v0.x; acc.y += v0.y; acc.z += v0.z; acc.w += v0.w;
        }
        acc.x += __shfl_xor(acc.x, 32, 64);
        acc.y += __shfl_xor(acc.y, 32, 64);
        acc.z += __shfl_xor(acc.z, 32, 64);
        acc.w += __shfl_xor(acc.w, 32, 64);
        int cnt = e - s;
        float inv = 1.0f / (float)(cnt > 1 ? cnt : 1);
        if (half == 0) {
            ((float4*)mb[hh])[li] = make_float4(acc.x * inv, acc.y * inv, acc.z * inv, acc.w * inv);
        }
    }
    __syncthreads();

    {
        int j = t & 63, wg = t >> 6;
        const float* Wg = aw1 + 128 * 64;      // [128][64], L2-hot
        float b1 = ab1[j];
        float a0 = b1, a1 = b1, a2 = b1, a3 = b1;
        #pragma unroll 8
        for (int k = 0; k < 128; ++k) {
            float w = Wg[k * 64 + j];
            a0 += mb[wg * 4 + 0][k] * w;
            a1 += mb[wg * 4 + 1][k] * w;
            a2 += mb[wg * 4 + 2][k] * w;
            a3 += mb[wg * 4 + 3][k] * w;
        }
        int h = h0 + wg * 4;
        if (h + 0 < H_HERBS) mpart[(size_t)(h + 0) * 64 + j] = a0;
        if (h + 1 < H_HERBS) mpart[(size_t)(h + 1) * 64 + j] = a1;
        if (h + 2 < H_HERBS) mpart[(size_t)(h + 2) * 64 + j] = a2;
        if (h + 3 < H_HERBS) mpart[(size_t)(h + 3) * 64 + j] = a3;
    }
}

// ---------------- K2b: mpart from precomputed mean (one side) -------------
__global__ __launch_bounds__(256) void k_mpart_one(
        const float* __restrict__ meanG, const float* __restrict__ aw1,
        const float* __restrict__ ab1, float* __restrict__ mpart) {
    __shared__ float Wl[128 * 64];
    __shared__ float mb[64 * 128];
    int h0 = blockIdx.x * 64;
    int t = threadIdx.x;

    const float4* Wsrc = (const float4*)(aw1 + 128 * 64);
    float4* Wl4 = (float4*)Wl;
    #pragma unroll
    for (int q = 0; q < 8; ++q) Wl4[t + 256 * q] = Wsrc[t + 256 * q];
    float4* mb4 = (float4*)mb;
    const float4* mG4 = (const float4*)meanG;
    #pragma unroll
    for (int q = 0; q < 8; ++q) {
        int ent = t + 256 * q;
        int hl = ent >> 5, kq = ent & 31;
        int h = h0 + hl;
        mb4[ent] = (h < H_HERBS) ? mG4[(size_t)h * 32 + kq] : make_float4(0.f, 0.f, 0.f, 0.f);
    }
    __syncthreads();

    int j = t & 63, hg = t >> 6;
    float b1 = ab1[j];
    #pragma unroll
    for (int ii = 0; ii < 4; ++ii) {
        int hl0 = hg * 16 + ii * 4;
        float a0 = 0.f, a1 = 0.f, a2 = 0.f, a3 = 0.f;
        for (int k = 0; k < 128; ++k) {
            float w = Wl[k * 64 + j];
            a0 += mb[(hl0 + 0) * 128 + k] * w;
            a1 += mb[(hl0 + 1) * 128 + k] * w;
            a2 += mb[(hl0 + 2) * 128 + k] * w;
            a3 += mb[(hl0 + 3) * 128 + k] * w;
        }
        int h = h0 + hl0;
        if (h + 0 < H_HERBS) mpart[(size_t)(h + 0) * 64 + j] = b1 + a0;
        if (h + 1 < H_HERBS) mpart[(size_t)(h + 1) * 64 + j] = b1 + a1;
        if (h + 2 < H_HERBS) mpart[(size_t)(h + 2) * 64 + j] = b1 + a2;
        if (h + 3 < H_HERBS) mpart[(size_t)(h + 3) * 64 + j] = b1 + a3;
    }
}

// ---------------- K3: attention scores via MFMA, one side -----------------
__global__ __launch_bounds__(256) void k_scores_one(
        const float* __restrict__ X, const int* __restrict__ idx,
        const float* __restrict__ mpart,
        const float* __restrict__ aw1, const float* __restrict__ aw2,
        const float* __restrict__ ab2,
        float* __restrict__ scores, int n) {
    int t = threadIdx.x;
    int l = t & 63, wid = t >> 6;
    int c = l & 15, kg = l >> 4;

    union ABu { bf16x8 v; unsigned u[4]; };

    ABu wf[4][4];
    #pragma unroll
    for (int kb = 0; kb < 4; ++kb) {
        int k0 = kb * 32 + kg * 8;
        #pragma unroll
        for (int nb = 0; nb < 4; ++nb) {
            int j = nb * 16 + c;
            #pragma unroll
            for (int e = 0; e < 4; ++e) {
                wf[kb][nb].u[e] = pack2bf(aw1[(size_t)(k0 + 2 * e)     * 64 + j],
                                          aw1[(size_t)(k0 + 2 * e + 1) * 64 + j]);
            }
        }
    }
    float a2[4];
    #pragma unroll
    for (int nb = 0; nb < 4; ++nb) a2[nb] = aw2[nb * 16 + c];
    float b2s = ab2[0];

    for (int pass = 0; pass < 4; ++pass) {
        long r0 = (long)blockIdx.x * 256 + pass * 64 + wid * 16;
        if (r0 >= n) break;
        long myrow = r0 + c;
        if (myrow >= n) myrow = n - 1;
        const float4* Xr = (const float4*)(X + (size_t)myrow * DIM);

        ABu af[4];
        #pragma unroll
        for (int kb = 0; kb < 4; ++kb) {
            float4 a = Xr[kb * 8 + kg * 2];
            float4 b = Xr[kb * 8 + kg * 2 + 1];
            af[kb].u[0] = pack2bf(a.x, a.y);
            af[kb].u[1] = pack2bf(a.z, a.w);
            af[kb].u[2] = pack2bf(b.x, b.y);
            af[kb].u[3] = pack2bf(b.z, b.w);
        }

        f32x4 acc[4];
        #pragma unroll
        for (int nb = 0; nb < 4; ++nb) { acc[nb].x = 0.f; acc[nb].y = 0.f; acc[nb].z = 0.f; acc[nb].w = 0.f; }
        #pragma unroll
        for (int kb = 0; kb < 4; ++kb) {
            #pragma unroll
            for (int nb = 0; nb < 4; ++nb) {
                acc[nb] = __builtin_amdgcn_mfma_f32_16x16x32_bf16(af[kb].v, wf[kb][nb].v, acc[nb], 0, 0, 0);
            }
        }

        int rgrp = kg * 4;
        float part[4] = {0.f, 0.f, 0.f, 0.f};
        #pragma unroll
        for (int reg = 0; reg < 4; ++reg) {
            long rr = r0 + rgrp + reg;
            bool v = rr < n;
            int h = v ? idx[rr] : 0;
            const float* mp = mpart + (size_t)h * 64;
            #pragma unroll
            for (int nb = 0; nb < 4; ++nb) {
                float hv = acc[nb][reg] + mp[nb * 16 + c];
                hv = hv > 0.f ? hv : 0.2f * hv;
                part[reg] += hv * a2[nb];
            }
        }
        #pragma unroll
        for (int reg = 0; reg < 4; ++reg) {
            float p = part[reg];
            p += __shfl_xor(p, 1, 64);
            p += __shfl_xor(p, 2, 64);
            p += __shfl_xor(p, 4, 64);
            p += __shfl_xor(p, 8, 64);
            part[reg] = p;
        }
        if (c == 0) {
            #pragma unroll
            for (int reg = 0; reg < 4; ++reg) {
                long rr = r0 + rgrp + reg;
                if (rr < n) scores[rr] = part[reg] + b2s;
            }
        }
    }
}

// ---------------- K4: softmax + weighted sum, one side; optional mean -----
template <bool WITH_MEAN>
__global__ __launch_bounds__(64) void k_attn_one(
        const float* __restrict__ X, const int* __restrict__ start,
        const float* __restrict__ scores,
        float* __restrict__ out, float* __restrict__ meanOut) {
    int h = blockIdx.x;
    int lane = threadIdx.x;
    int half = lane >> 5, li = lane & 31;
    int s = start[h], e = start[h + 1];
    const float4* X4 = (const float4*)X;
    float4 acc = make_float4(0.f, 0.f, 0.f, 0.f);
    float4 accS = make_float4(0.f, 0.f, 0.f, 0.f);
    if (e > s) {
        float mx = -INFINITY;
        for (int r = s + lane; r < e; r += 64) mx = fmaxf(mx, scores[r]);
        #pragma unroll
        for (int o = 32; o; o >>= 1) mx = fmaxf(mx, __shfl_xor(mx, o, 64));
        float sum = 0.f;
        for (int r = s + lane; r < e; r += 64) sum += __expf(scores[r] - mx);
        #pragma unroll
        for (int o = 32; o; o >>= 1) sum += __shfl_xor(sum, o, 64);
        float invden = 1.0f / (sum + 1e-16f);

        int r = s + half;
        for (; r + 6 < e; r += 8) {
            float w0 = __expf(scores[r]     - mx) * invden;
            float w1 = __expf(scores[r + 2] - mx) * invden;
            float w2 = __expf(scores[r + 4] - mx) * invden;
            float w3 = __expf(scores[r + 6] - mx) * invden;
            float4 v0 = X4[(size_t)r * 32 + li];
            float4 v1 = X4[(size_t)(r + 2) * 32 + li];
            float4 v2 = X4[(size_t)(r + 4) * 32 + li];
            float4 v3 = X4[(size_t)(r + 6) * 32 + li];
            acc.x += (w0 * v0.x + w1 * v1.x) + (w2 * v2.x + w3 * v3.x);
            acc.y += (w0 * v0.y + w1 * v1.y) + (w2 * v2.y + w3 * v3.y);
            acc.z += (w0 * v0.z + w1 * v1.z) + (w2 * v2.z + w3 * v3.z);
            acc.w += (w0 * v0.w + w1 * v1.w) + (w2 * v2.w + w3 * v3.w);
            if (WITH_MEAN) {
                accS.x += (v0.x + v1.x) + (v2.x + v3.x);
                accS.y += (v0.y + v1.y) + (v2.y + v3.y);
                accS.z += (v0.z + v1.z) + (v2.z + v3.z);
                accS.w += (v0.w + v1.w) + (v2.w + v3.w);
            }
        }
        for (; r < e; r += 2) {
            float w0 = __expf(scores[r] - mx) * invden;
            float4 v0 = X4[(size_t)r * 32 + li];
            acc.x += w0 * v0.x; acc.y += w0 * v0.y;
            acc.z += w0 * v0.z; acc.w += w0 * v0.w;
            if (WITH_MEAN) {
                accS.x += v0.x; accS.y += v0.y; accS.z += v0.z; accS.w += v0.w;
            }
        }
    }
    acc.x += __shfl_xor(acc.x, 32, 64);
    acc.y += __shfl_xor(acc.y, 32, 64);
    acc.z += __shfl_xor(acc.z, 32, 64);
    acc.w += __shfl_xor(acc.w, 32, 64);
    if (WITH_MEAN) {
        accS.x += __shfl_xor(accS.x, 32, 64);
        accS.y += __shfl_xor(accS.y, 32, 64);
        accS.z += __shfl_xor(accS.z, 32, 64);
        accS.w += __shfl_xor(accS.w, 32, 64);
    }
    if (half == 0) {
        ((float4*)out)[(size_t)h * 32 + li] = acc;
        if (WITH_MEAN) {
            int cnt = e - s;
            float inv = 1.0f / (float)(cnt > 1 ? cnt : 1);
            ((float4*)meanOut)[(size_t)h * 32 + li] =
                make_float4(accS.x * inv, accS.y * inv, accS.z * inv, accS.w * inv);
        }
    }
}

// ---------------- K5: fusion MLP on matrix cores ---------------------------
__global__ __launch_bounds__(256) void k_fusion_mfma(
        const float* __restrict__ HA, const float* __restrict__ HB,
        const uint4* __restrict__ w1bf, const uint4* __restrict__ w2bf,
        const float* __restrict__ fb1, const float* __restrict__ fb2,
        float* __restrict__ out) {
    __shared__ float hid[32 * 256];   // 32 KB, swizzled
    int t = threadIdx.x, wid = t >> 6, l = t & 63, c = l & 15, kg = l >> 4;
    int h0 = blockIdx.x * 32;
    int ms = wid & 1, nh = wid >> 1;

    union ABu { bf16x8 v; unsigned u[4]; uint4 q; };

    {
        int rowl = ms * 16 + c;
        int h = h0 + rowl;
        bool hv = h < H_HERBS;
        const float* pa = HA + (size_t)(hv ? h : h0) * DIM;
        const float* pb = HB + (size_t)(hv ? h : h0) * DIM;

        f32x4 acc[8];
        #pragma unroll
        for (int nt = 0; nt < 8; ++nt) { acc[nt].x = 0.f; acc[nt].y = 0.f; acc[nt].z = 0.f; acc[nt].w = 0.f; }

        #pragma unroll
        for (int kt = 0; kt < 16; ++kt) {
            int k0 = kt * 32 + kg * 8;
            int range = k0 >> 7, off = k0 & 127;
            float f[8];
            if (range == 0) {
                float4 a0 = *(const float4*)(pa + off), a1 = *(const float4*)(pa + off + 4);
                f[0] = a0.x; f[1] = a0.y; f[2] = a0.z; f[3] = a0.w;
                f[4] = a1.x; f[5] = a1.y; f[6] = a1.z; f[7] = a1.w;
            } else if (range == 1) {
                float4 b0 = *(const float4*)(pb + off), b1 = *(const float4*)(pb + off + 4);
                f[0] = b0.x; f[1] = b0.y; f[2] = b0.z; f[3] = b0.w;
                f[4] = b1.x; f[5] = b1.y; f[6] = b1.z; f[7] = b1.w;
            } else if (range == 2) {
                float4 a0 = *(const float4*)(pa + off), a1 = *(const float4*)(pa + off + 4);
                float4 b0 = *(const float4*)(pb + off), b1 = *(const float4*)(pb + off + 4);
                f[0] = a0.x * b0.x; f[1] = a0.y * b0.y; f[2] = a0.z * b0.z; f[3] = a0.w * b0.w;
                f[4] = a1.x * b1.x; f[5] = a1.y * b1.y; f[6] = a1.z * b1.z; f[7] = a1.w * b1.w;
            } else {
                float4 a0 = *(const float4*)(pa + off), a1 = *(const float4*)(pa + off + 4);
                float4 b0 = *(const float4*)(pb + off), b1 = *(const float4*)(pb + off + 4);
                f[0] = fabsf(a0.x - b0.x); f[1] = fabsf(a0.y - b0.y);
                f[2] = fabsf(a0.z - b0.z); f[3] = fabsf(a0.w - b0.w);
                f[4] = fabsf(a1.x - b1.x); f[5] = fabsf(a1.y - b1.y);
                f[6] = fabsf(a1.z - b1.z); f[7] = fabsf(a1.w - b1.w);
            }
            ABu af;
            af.u[0] = pack2bf(f[0], f[1]); af.u[1] = pack2bf(f[2], f[3]);
            af.u[2] = pack2bf(f[4], f[5]); af.u[3] = pack2bf(f[6], f[7]);
            #pragma unroll
            for (int nt = 0; nt < 8; ++nt) {
                ABu bfr; bfr.q = w1bf[(size_t)(kt * 16 + nh * 8 + nt) * 64 + l];
                acc[nt] = __builtin_amdgcn_mfma_f32_16x16x32_bf16(af.v, bfr.v, acc[nt], 0, 0, 0);
            }
        }

        #pragma unroll
        for (int nt = 0; nt < 8; ++nt) {
            int j = nh * 128 + nt * 16 + c;
            float b1 = fb1[j];
            #pragma unroll
            for (int reg = 0; reg < 4; ++reg) {
                int row = ms * 16 + kg * 4 + reg;
                float v = fmaxf(acc[nt][reg] + b1, 0.f);
                hid[row * 256 + (j ^ ((row & 7) << 3))] = v;
            }
        }
    }
    __syncthreads();

    {
        int rowl = ms * 16 + c;
        f32x4 acc2[4];
        #pragma unroll
        for (int nt = 0; nt < 4; ++nt) { acc2[nt].x = 0.f; acc2[nt].y = 0.f; acc2[nt].z = 0.f; acc2[nt].w = 0.f; }

        #pragma unroll
        for (int kt = 0; kt < 8; ++kt) {
            int j0 = kt * 32 + kg * 8;
            int widx = rowl * 256 + (j0 ^ ((rowl & 7) << 3));
            float4 h0v = *(const float4*)&hid[widx];
            float4 h1v = *(const float4*)&hid[widx + 4];
            ABu af;
            af.u[0] = pack2bf(h0v.x, h0v.y); af.u[1] = pack2bf(h0v.z, h0v.w);
            af.u[2] = pack2bf(h1v.x, h1v.y); af.u[3] = pack2bf(h1v.z, h1v.w);
            #pragma unroll
            for (int nt = 0; nt < 4; ++nt) {
                ABu bfr; bfr.q = w2bf[(size_t)(kt * 8 + nh * 4 + nt) * 64 + l];
                acc2[nt] = __builtin_amdgcn_mfma_f32_16x16x32_bf16(af.v, bfr.v, acc2[nt], 0, 0, 0);
            }
        }

        #pragma unroll
        for (int nt = 0; nt < 4; ++nt) {
            int j = nh * 64 + nt * 16 + c;
            float b2 = fb2[j];
            #pragma unroll
            for (int reg = 0; reg < 4; ++reg) {
                int row = ms * 16 + kg * 4 + reg;
                int h = h0 + row;
                if (h < H_HERBS) out[(size_t)h * DIM + j] = acc2[nt][reg] + b2;
            }
        }
    }
}

extern "C" void kernel_launch(void* const* d_in, const int* in_sizes, int n_in,
                              void* d_out, int out_size, void* d_ws, size_t ws_size,
                              hipStream_t stream) {
    const float* hA  = (const float*)d_in[0];
    const float* hB  = (const float*)d_in[1];
    const int*   idxA = (const int*)d_in[2];
    const int*   idxB = (const int*)d_in[3];
    const float* aw1 = (const float*)d_in[5];
    const float* ab1 = (const float*)d_in[6];
    const float* aw2 = (const float*)d_in[7];
    const float* ab2 = (const float*)d_in[8];
    const float* fw1 = (const float*)d_in[9];
    const float* fb1 = (const float*)d_in[10];
    const float* fw2 = (const float*)d_in[11];
    const float* fb2 = (const float*)d_in[12];

    int nA = in_sizes[0] / DIM;
    int nB = in_sizes[1] / DIM;

    float* out  = (float*)d_out;
    float* outI = out;                                  // fusion output (last write)
    float* outA = out + (size_t)H_HERBS * DIM;
    float* outB = out + (size_t)2 * H_HERBS * DIM;
    float* meanA = outI;                                // scratch; overwritten by fusion

    char* w = (char*)d_ws;
    auto carve = [&](size_t bytes) { char* p = w; w += (bytes + 255) & ~(size_t)255; return p; };
    int*   startA  = (int*)carve((size_t)(H_HERBS + 1) * sizeof(int));
    int*   startB  = (int*)carve((size_t)(H_HERBS + 1) * sizeof(int));
    float* mpartA  = (float*)carve((size_t)H_HERBS * 64 * sizeof(float));
    float* mpartB  = (float*)carve((size_t)H_HERBS * 64 * sizeof(float));
    float* scoresA = (float*)carve((size_t)nA * sizeof(float));
    float* scoresB = (float*)carve((size_t)nB * sizeof(float));
    uint4* w1bf    = (uint4*)carve((size_t)256 * 64 * sizeof(uint4));   // 256 KB
    uint4* w2bf    = (uint4*)carve((size_t)64 * 64 * sizeof(uint4));    // 64 KB

    int gridA = (nA + 255) / 256;
    int gridB = (nB + 255) / 256;
    int nhb16 = (H_HERBS + 15) / 16;
    int nhb64 = (H_HERBS + 63) / 64;

    k_starts<<<(H_HERBS + 1 + 255) / 256, 256, 0, stream>>>(idxA, idxB, nA, nB, startA, startB);
    k_packw<<<320, 64, 0, stream>>>(fw1, fw2, w1bf, w2bf);

    // ---- side-sequential schedule for L3 residency ----
    // D1: meanB (reads XB cold) -> mpartA
    k_mean_proj<<<nhb16, 256, 0, stream>>>(hB, startB, aw1, ab1, mpartA);
    // D2: scoresA (reads XA cold; XA now L3-resident)
    k_scores_one<<<gridA, 256, 0, stream>>>(hA, idxA, mpartA, aw1, aw2, ab2, scoresA, nA);
    // D3: attnA + fused meanA (reads XA hot) -> outA, meanA
    k_attn_one<true><<<H_HERBS, 64, 0, stream>>>(hA, startA, scoresA, outA, meanA);
    // D4: mpartB from meanA (tiny)
    k_mpart_one<<<nhb64, 256, 0, stream>>>(meanA, aw1, ab1, mpartB);
    // D5: scoresB (reads XB cold; XB now L3-resident)
    k_scores_one<<<gridB, 256, 0, stream>>>(hB, idxB, mpartB, aw1, aw2, ab2, scoresB, nB);
    // D6: attnB (reads XB hot) -> outB
    k_attn_one<false><<<H_HERBS, 64, 0, stream>>>(hB, startB, scoresB, outB, nullptr);
    // D7: fusion MLP (overwrites outI/meanA)
    k_fusion_mfma<<<(H_HERBS + 31) / 32, 256, 0, stream>>>(outA, outB, w1bf, w2bf, fb1, fb2, outI);
}